// Round 5
// baseline (276.629 us; speedup 1.0000x reference)
//
#include <hip/hip_runtime.h>
#include <hip/hip_bf16.h>

#define D 384
#define NROWS 16384
#define BATCH 4
#define MG 512
#define RTOT (BATCH * NROWS) /* 65536 */
#define NC (2 * D)           /* 768 combined B rows: g|f panels per j-block */
#define JB 64                /* j-columns per block */
#define NJB (D / JB)         /* 6 */
#define BM 128
#define NKT (D / 32)         /* 12 */
#define NMT (RTOT / BM)      /* 512 */

typedef __attribute__((ext_vector_type(8))) short bf16x8;
typedef __attribute__((ext_vector_type(4))) float f32x4;

static __device__ __forceinline__ unsigned short f2bf(float f) {
  unsigned int u = __float_as_uint(f);
  unsigned int r = u + 0x7fffu + ((u >> 16) & 1u); // RNE
  return (unsigned short)(r >> 16);
}
static __device__ __forceinline__ unsigned int cvtpk(float lo, float hi) {
  unsigned int r;
  asm("v_cvt_pk_bf16_f32 %0, %1, %2" : "=v"(r) : "v"(lo), "v"(hi));
  return r;
}
static __device__ __forceinline__ float frcp(float f) {
  float r;
  asm("v_rcp_f32 %0, %1" : "=v"(r) : "v"(f));
  return r;
}

// ---------------- fused preprocessing ----------------
// block 0: CSR build (512 threads). blocks 1..63: zero s1/s2.
// blocks 64..127: build wt2 (g|f panels per j-block) + hw bf16.
__global__ __launch_bounds__(512) void k_prep(
    const int* __restrict__ ii, const float* __restrict__ g_w,
    const float* __restrict__ f_w, const float* __restrict__ h_w,
    unsigned short* __restrict__ wt2, unsigned short* __restrict__ hw,
    int* __restrict__ csr_rows, int* __restrict__ grp_sorted,
    float* __restrict__ s12) {
  __shared__ int cnt[MG];
  __shared__ int scan[MG];
  const int blk = blockIdx.x;
  const int t = threadIdx.x; // 512 threads
  if (blk == 0) {
    cnt[t] = 0;
    __syncthreads();
    for (int n = t; n < NROWS; n += MG) atomicAdd(&cnt[ii[n]], 1);
    __syncthreads();
    const int v = cnt[t];
    scan[t] = v;
    __syncthreads();
#pragma unroll
    for (int o = 1; o < MG; o <<= 1) { // Hillis-Steele inclusive scan
      int u = (t >= o) ? scan[t - o] : 0;
      __syncthreads();
      scan[t] += u;
      __syncthreads();
    }
    cnt[t] = scan[t] - v; // exclusive
    __syncthreads();
    for (int n = t; n < NROWS; n += MG) {
      int m = ii[n];
      int pos = atomicAdd(&cnt[m], 1);
      csr_rows[pos] = n;
      grp_sorted[pos] = m;
    }
  } else if (blk < 64) {
    const int tot4 = 2 * BATCH * MG * D / 4; // 393216 float4
    float4 z = {0.f, 0.f, 0.f, 0.f};
    for (int i = (blk - 1) * 512 + t; i < tot4; i += 63 * 512) ((float4*)s12)[i] = z;
  } else {
    const int tid0 = (blk - 64) * 512 + t;
    const int stride = 64 * 512;
    for (int idx = tid0; idx < NC * D; idx += stride) {
      int jblk = idx / (128 * D);
      int rem = idx % (128 * D);
      int c = rem / D, k = rem % D;
      int j = jblk * JB + (c & 63);
      float v = (c < JB) ? g_w[j * D + k] : f_w[j * D + k];
      wt2[idx] = f2bf(v);
    }
    for (int idx = tid0; idx < D * D; idx += stride) hw[idx] = f2bf(h_w[idx]);
  }
}

// ---------------- fused GEMM + exp + segment-reduce, barrier-free ----------------
// No LDS: MFMA fragments read directly from global (A: f32 x rows CSR-gathered,
// converted in-register via v_cvt_pk_bf16_f32; B: bf16 panels, L2-hot).
// All k-offsets are compile-time immediates folded into the global offset.
// Manual 2-step software pipeline with named register sets.
__global__ __launch_bounds__(256, 2) void k_gemm1(
    const float* __restrict__ x, const unsigned short* __restrict__ wt2,
    const float* __restrict__ g_b, const float* __restrict__ f_b,
    const int* __restrict__ csr_rows, const int* __restrict__ grp_sorted,
    float* __restrict__ s1acc, float* __restrict__ s2acc) {
  // bijective XCD swizzle; j-block varies fastest within an XCD (A-tile L2 reuse)
  const int wg = blockIdx.x; // 0..3071
  const int xcd = wg & 7;
  const int ix = wg >> 3; // 0..383
  const int mt = xcd * (NMT / 8) + ix / NJB;
  const int jb = ix % NJB;
  const int b = mt >> 7;          // batch
  const int ib = (mt & 127) * BM; // per-batch CSR base index
  const int j0 = jb * JB;

  const int tid = threadIdx.x;
  const int lane = tid & 63, wid = tid >> 6;
  const int wr = wid >> 1, wc = wid & 1;

  // per-lane fragment base pointers
  const float* aP[4];
#pragma unroll
  for (int m = 0; m < 4; m++) {
    const int r = csr_rows[ib + wr * 64 + m * 16 + (lane & 15)];
    aP[m] = x + (size_t)(b * NROWS + r) * D + (lane >> 4) * 8;
  }
  const unsigned short* bP[4];
#pragma unroll
  for (int n = 0; n < 4; n++) {
    const int c = (n < 2) ? (wc * 32 + n * 16) : (64 + wc * 32 + (n - 2) * 16);
    bP[n] = wt2 + (size_t)jb * (128 * D) + (size_t)(c + (lane & 15)) * D + (lane >> 4) * 8;
  }

  f32x4 acc[4][4];
#pragma unroll
  for (int m = 0; m < 4; m++)
#pragma unroll
    for (int n = 0; n < 4; n++) acc[m][n] = (f32x4){0.f, 0.f, 0.f, 0.f};

  float4 Alo0[4], Ahi0[4], Alo1[4], Ahi1[4];
  bf16x8 B0[4], B1[4];

#define LOADA(L, H, kt)                                                                  \
  _Pragma("unroll") for (int m = 0; m < 4; m++) {                                        \
    L[m] = *(const float4*)(aP[m] + (kt) * 32);                                          \
    H[m] = *(const float4*)(aP[m] + (kt) * 32 + 4);                                      \
  }
#define LOADB(Bv, kt)                                                                    \
  _Pragma("unroll") for (int n = 0; n < 4; n++) Bv[n] =                                  \
      *(const bf16x8*)(bP[n] + (kt) * 32);
#define STEP(L, H, Bv)                                                                   \
  _Pragma("unroll") for (int m = 0; m < 4; m++) {                                        \
    int4 p;                                                                              \
    p.x = cvtpk(L[m].x, L[m].y);                                                         \
    p.y = cvtpk(L[m].z, L[m].w);                                                         \
    p.z = cvtpk(H[m].x, H[m].y);                                                         \
    p.w = cvtpk(H[m].z, H[m].w);                                                         \
    bf16x8 af = *(bf16x8*)&p;                                                            \
    _Pragma("unroll") for (int n = 0; n < 4; n++) acc[m][n] =                            \
        __builtin_amdgcn_mfma_f32_16x16x32_bf16(af, Bv[n], acc[m][n], 0, 0, 0);          \
  }

  LOADA(Alo0, Ahi0, 0)
  LOADB(B0, 0)
#pragma unroll
  for (int kt = 0; kt < NKT; kt += 2) {
    LOADA(Alo1, Ahi1, kt + 1)
    LOADB(B1, kt + 1)
    STEP(Alo0, Ahi0, B0)
    if (kt + 2 < NKT) {
      LOADA(Alo0, Ahi0, kt + 2)
      LOADB(B0, kt + 2)
    }
    STEP(Alo1, Ahi1, B1)
  }

  // ---- epilogue: e = exp(logit+gb); fxe = (fx+fb)*e; per-group reduce ----
  const int jA = j0 + wc * 32 + (lane & 15); // cols for n=0 (g) / n=2 (f)
  const float gb0 = g_b[jA], gb1 = g_b[jA + 16];
  const float fb0 = f_b[jA], fb1 = f_b[jA + 16];

  int gmr[4][4];
#pragma unroll
  for (int m = 0; m < 4; m++)
#pragma unroll
    for (int r = 0; r < 4; r++)
      gmr[m][r] = grp_sorted[ib + wr * 64 + m * 16 + (lane >> 4) * 4 + r];

#pragma unroll
  for (int m = 0; m < 4; m++)
#pragma unroll
    for (int r = 0; r < 4; r++) {
      const float e0 = expf(acc[m][0][r] + gb0);
      const float e1 = expf(acc[m][1][r] + gb1);
      const float f0 = acc[m][2][r] + fb0;
      const float f1 = acc[m][3][r] + fb1;
      acc[m][0][r] = e0; acc[m][1][r] = e1;
      acc[m][2][r] = f0 * e0; acc[m][3][r] = f1 * e1;
    }

  const int gLo = grp_sorted[ib + wr * 64], gHi = grp_sorted[ib + wr * 64 + 63];
  for (int g = gLo; g <= gHi; ++g) {
    float v0 = 0.f, v1 = 0.f, v2 = 0.f, v3 = 0.f;
#pragma unroll
    for (int m = 0; m < 4; m++)
#pragma unroll
      for (int r = 0; r < 4; r++)
        if (gmr[m][r] == g) {
          v0 += acc[m][0][r]; v1 += acc[m][1][r];
          v2 += acc[m][2][r]; v3 += acc[m][3][r];
        }
    v0 += __shfl_xor(v0, 16); v0 += __shfl_xor(v0, 32);
    v1 += __shfl_xor(v1, 16); v1 += __shfl_xor(v1, 32);
    v2 += __shfl_xor(v2, 16); v2 += __shfl_xor(v2, 32);
    v3 += __shfl_xor(v3, 16); v3 += __shfl_xor(v3, 32);
    if (lane < 16) {
      float* s1p = s1acc + ((size_t)(b * MG + g)) * D + j0 + wc * 32 + lane;
      float* s2p = s2acc + ((size_t)(b * MG + g)) * D + j0 + wc * 32 + lane;
      atomicAdd(s1p, v0);
      atomicAdd(s1p + 16, v1);
      atomicAdd(s2p, v2);
      atomicAdd(s2p + 16, v3);
    }
  }
}

// ---------------- small GEMM with fused normalize: Outpre = (s2/(s1+eps)) @ h_w^T + h_b ----------------
__global__ __launch_bounds__(256) void k_gemm2(
    const float* __restrict__ s1, const float* __restrict__ s2,
    const unsigned short* __restrict__ hw, const float* __restrict__ h_b,
    float* __restrict__ outpre) {
  const int tid = threadIdx.x, lane = tid & 63, wid = tid >> 6;
  const int r0 = blockIdx.y * 16;
  const int c0 = blockIdx.x * 64 + wid * 16;
  f32x4 acc = (f32x4){0.f, 0.f, 0.f, 0.f};
  const int arow = r0 + (lane & 15);
  const float* s1p = s1 + (size_t)arow * D + (lane >> 4) * 8;
  const float* s2p = s2 + (size_t)arow * D + (lane >> 4) * 8;
  const unsigned short* bRow = hw + (size_t)(c0 + (lane & 15)) * D + (lane >> 4) * 8;
#pragma unroll
  for (int kt = 0; kt < D / 32; kt++) {
    float4 u0 = *(const float4*)(s1p + kt * 32);
    float4 u1 = *(const float4*)(s1p + kt * 32 + 4);
    float4 w0 = *(const float4*)(s2p + kt * 32);
    float4 w1 = *(const float4*)(s2p + kt * 32 + 4);
    int4 yi;
    yi.x = cvtpk(w0.x * frcp(u0.x + 1e-6f), w0.y * frcp(u0.y + 1e-6f));
    yi.y = cvtpk(w0.z * frcp(u0.z + 1e-6f), w0.w * frcp(u0.w + 1e-6f));
    yi.z = cvtpk(w1.x * frcp(u1.x + 1e-6f), w1.y * frcp(u1.y + 1e-6f));
    yi.w = cvtpk(w1.z * frcp(u1.z + 1e-6f), w1.w * frcp(u1.w + 1e-6f));
    bf16x8 af = *(bf16x8*)&yi;
    bf16x8 bf_ = *(const bf16x8*)(bRow + kt * 32);
    acc = __builtin_amdgcn_mfma_f32_16x16x32_bf16(af, bf_, acc, 0, 0, 0);
  }
  const int col = c0 + (lane & 15);
  const float hb = h_b[col];
#pragma unroll
  for (int r = 0; r < 4; r++) {
    const int row = r0 + (lane >> 4) * 4 + r;
    outpre[(size_t)row * D + col] = acc[r] + hb;
  }
}

// ---------------- gather rows ----------------
__global__ void k_gather(const float* __restrict__ outpre, const int* __restrict__ ii,
                         float* __restrict__ out) {
  const long total4 = (long)RTOT * (D / 4); // 96 float4 per row
  for (long i = blockIdx.x * (long)blockDim.x + threadIdx.x; i < total4;
       i += (long)gridDim.x * blockDim.x) {
    const long row = i / (D / 4);
    const int q = (int)(i % (D / 4));
    const int b = (int)(row >> 14);
    const int n = (int)(row & (NROWS - 1));
    const int g = ii[n];
    ((float4*)out)[i] = ((const float4*)outpre)[((size_t)(b * MG + g)) * (D / 4) + q];
  }
}

extern "C" void kernel_launch(void* const* d_in, const int* in_sizes, int n_in,
                              void* d_out, int out_size, void* d_ws, size_t ws_size,
                              hipStream_t stream) {
  const float* x = (const float*)d_in[0];
  const int* ii = (const int*)d_in[1];
  const float* f_w = (const float*)d_in[2];
  const float* f_b = (const float*)d_in[3];
  const float* g_w = (const float*)d_in[4];
  const float* g_b = (const float*)d_in[5];
  const float* h_w = (const float*)d_in[6];
  const float* h_b = (const float*)d_in[7];
  float* out = (float*)d_out;

  char* ws = (char*)d_ws;
  size_t off = 0;
  auto alloc = [&](size_t bytes) {
    size_t p = off;
    off = (off + bytes + 255) & ~(size_t)255;
    return p;
  };
  unsigned short* wt2 = (unsigned short*)(ws + alloc((size_t)NC * D * 2));
  unsigned short* hw = (unsigned short*)(ws + alloc((size_t)D * D * 2));
  float* s1acc = (float*)(ws + alloc((size_t)BATCH * MG * D * 4)); // 3 MB
  float* s2acc = (float*)(ws + alloc((size_t)BATCH * MG * D * 4)); // contiguous after s1acc
  float* outpre = (float*)(ws + alloc((size_t)BATCH * MG * D * 4));
  int* csr_rows = (int*)(ws + alloc((size_t)NROWS * 4));
  int* grp_sorted = (int*)(ws + alloc((size_t)NROWS * 4));

  k_prep<<<dim3(128), dim3(512), 0, stream>>>(ii, g_w, f_w, h_w, wt2, hw, csr_rows,
                                              grp_sorted, s1acc);
  k_gemm1<<<dim3(NJB * NMT), dim3(256), 0, stream>>>(x, wt2, g_b, f_b, csr_rows,
                                                     grp_sorted, s1acc, s2acc);
  k_gemm2<<<dim3(D / 64, (BATCH * MG) / 16), dim3(256), 0, stream>>>(s1acc, s2acc, hw, h_b,
                                                                     outpre);
  k_gather<<<dim3(4096), dim3(256), 0, stream>>>(outpre, ii, out);
}

// Round 6
// 152.434 us; speedup vs baseline: 1.8147x; 1.8147x over previous
//
#include <hip/hip_runtime.h>
#include <hip/hip_bf16.h>

#define D 384
#define NROWS 16384
#define BATCH 4
#define MG 512
#define RTOT (BATCH * NROWS) /* 65536 */
#define NC (2 * D)           /* 768 combined B rows: g|f panels per j-block */
#define JB 64                /* j-columns per block */
#define NJB (D / JB)         /* 6 */
#define BM 128
#define BK 32
#define NKT (D / BK)         /* 12 */
#define NMT (RTOT / BM)      /* 512 */

typedef __attribute__((ext_vector_type(8))) short bf16x8;
typedef __attribute__((ext_vector_type(4))) float f32x4;

static __device__ __forceinline__ unsigned short f2bf(float f) {
  unsigned int u = __float_as_uint(f);
  unsigned int r = u + 0x7fffu + ((u >> 16) & 1u); // RNE
  return (unsigned short)(r >> 16);
}
static __device__ __forceinline__ unsigned int cvtpk(float lo, float hi) {
  unsigned int r;
  asm("v_cvt_pk_bf16_f32 %0, %1, %2" : "=v"(r) : "v"(lo), "v"(hi));
  return r;
}
static __device__ __forceinline__ float frcp(float f) {
  float r;
  asm("v_rcp_f32 %0, %1" : "=v"(r) : "v"(f));
  return r;
}

typedef __attribute__((address_space(1))) const void gvoid_t;
typedef __attribute__((address_space(3))) void lvoid_t;
static __device__ __forceinline__ void gl16(const void* g, void* l) {
  __builtin_amdgcn_global_load_lds((gvoid_t*)g, (lvoid_t*)l, 16, 0, 0);
}

// ---------------- fused preprocessing ----------------
// block 0: CSR build. blocks 1..63: zero s1/s2. blocks 64..127: wt2/hw bf16.
// blocks 128..1279: x f32 -> bf16.
__global__ __launch_bounds__(512) void k_prep(
    const int* __restrict__ ii, const float* __restrict__ x,
    const float* __restrict__ g_w, const float* __restrict__ f_w,
    const float* __restrict__ h_w, unsigned short* __restrict__ xb,
    unsigned short* __restrict__ wt2, unsigned short* __restrict__ hw,
    int* __restrict__ csr_rows, int* __restrict__ grp_sorted,
    float* __restrict__ s12) {
  __shared__ int cnt[MG];
  __shared__ int scan[MG];
  const int blk = blockIdx.x;
  const int t = threadIdx.x; // 512 threads
  if (blk == 0) {
    cnt[t] = 0;
    __syncthreads();
    for (int n = t; n < NROWS; n += MG) atomicAdd(&cnt[ii[n]], 1);
    __syncthreads();
    const int v = cnt[t];
    scan[t] = v;
    __syncthreads();
#pragma unroll
    for (int o = 1; o < MG; o <<= 1) { // Hillis-Steele inclusive scan
      int u = (t >= o) ? scan[t - o] : 0;
      __syncthreads();
      scan[t] += u;
      __syncthreads();
    }
    cnt[t] = scan[t] - v; // exclusive
    __syncthreads();
    for (int n = t; n < NROWS; n += MG) {
      int m = ii[n];
      int pos = atomicAdd(&cnt[m], 1);
      csr_rows[pos] = n;
      grp_sorted[pos] = m;
    }
  } else if (blk < 64) {
    const int tot4 = 2 * BATCH * MG * D / 4;
    float4 z = {0.f, 0.f, 0.f, 0.f};
    for (int i = (blk - 1) * 512 + t; i < tot4; i += 63 * 512) ((float4*)s12)[i] = z;
  } else if (blk < 128) {
    const int tid0 = (blk - 64) * 512 + t;
    const int stride = 64 * 512;
    for (int idx = tid0; idx < NC * D; idx += stride) {
      int jblk = idx / (128 * D);
      int rem = idx % (128 * D);
      int c = rem / D, k = rem % D;
      int j = jblk * JB + (c & 63);
      float v = (c < JB) ? g_w[j * D + k] : f_w[j * D + k];
      wt2[idx] = f2bf(v);
    }
    for (int idx = tid0; idx < D * D; idx += stride) hw[idx] = f2bf(h_w[idx]);
  } else {
    const long total4 = (long)RTOT * D / 4;
    for (long i = (long)(blk - 128) * 512 + t; i < total4; i += 1152L * 512) {
      float4 v = ((const float4*)x)[i];
      ushort4 o;
      o.x = f2bf(v.x); o.y = f2bf(v.y); o.z = f2bf(v.z); o.w = f2bf(v.w);
      ((ushort4*)xb)[i] = o;
    }
  }
}

// ---------------- fused GEMM + exp + segment-reduce ----------------
// R3 structure (best measured): gl16 A/B staging, 2-phase double-buffered
// K-loop. NEW: conflict-free XOR swizzle (T2, rule #21): LDS[row][slot]
// holds global chunk slot^((row>>1)&3); gl16 dest stays linear, source
// chunk is inverse-permuted; ds_read XORs the slot. All 64 lanes of a
// fragment read hit 64 distinct 16B cells -> pure 2-wrap (free).
__global__ __launch_bounds__(256, 4) void k_gemm1(
    const unsigned short* __restrict__ xb, const unsigned short* __restrict__ wt2,
    const float* __restrict__ g_b, const float* __restrict__ f_b,
    const int* __restrict__ csr_rows, const int* __restrict__ grp_sorted,
    float* __restrict__ s1acc, float* __restrict__ s2acc) {
  __shared__ __attribute__((aligned(16))) unsigned short As[2][BM * BK]; // 2 x 8 KB
  __shared__ __attribute__((aligned(16))) unsigned short Bs[2][BM * BK];
  __shared__ int grpS[BM];

  // bijective XCD swizzle; j-block varies fastest within an XCD (A-tile L2 reuse)
  const int wg = blockIdx.x; // 0..3071
  const int xcd = wg & 7;
  const int ix = wg >> 3; // 0..383
  const int mt = xcd * (NMT / 8) + ix / NJB;
  const int jb = ix % NJB;
  const int b = mt >> 7;          // batch
  const int ib = (mt & 127) * BM; // per-batch CSR base index
  const int j0 = jb * JB;

  const int tid = threadIdx.x;
  const int lane = tid & 63, wid = tid >> 6;
  const int wr = wid >> 1, wc = wid & 1;

  if (tid < BM) grpS[tid] = grp_sorted[ib + tid];

  // staging: wave wid covers tile rows wid*32..+31 as two 16-row chunks;
  // lane l -> row wid*32 + (l>>2) (+16), source 16B chunk (l&3)^((l>>3)&3)
  // (= slot ^ ((row>>1)&3), identical for both calls since +16 keeps row>>1&3).
  const int srow = wid * 32 + (lane >> 2);
  const int skb = (((lane & 3) ^ ((lane >> 3) & 3))) * 16;
  const int arow0 = b * NROWS + csr_rows[ib + srow];
  const int arow1 = b * NROWS + csr_rows[ib + srow + 16];
  const char* aS0 = (const char*)xb + (size_t)arow0 * (D * 2) + skb;
  const char* aS1 = (const char*)xb + (size_t)arow1 * (D * 2) + skb;
  const char* bS0 = (const char*)wt2 + (size_t)jb * (128 * D * 2) + (size_t)srow * (D * 2) + skb;
  const char* bS1 = bS0 + 16 * (D * 2);

  f32x4 acc[4][4];
#pragma unroll
  for (int m = 0; m < 4; m++)
#pragma unroll
    for (int n = 0; n < 4; n++) acc[m][n] = (f32x4){0.f, 0.f, 0.f, 0.f};

  // prologue: stage kt=0 into buf 0
  {
    char* ad = (char*)As[0] + wid * 2048;
    char* bd = (char*)Bs[0] + wid * 2048;
    gl16(aS0, ad); gl16(aS1, ad + 1024);
    gl16(bS0, bd); gl16(bS1, bd + 1024);
  }
  __syncthreads();

  // read-side swizzled 16B slot: (lane>>4) ^ ((row>>1)&3) = (lane>>4)^((lane>>1)&3)
  const int swz16 = (((lane >> 4) ^ ((lane >> 1) & 3))) * 16;

#pragma unroll 1
  for (int kt = 0; kt < NKT; ++kt) {
    const int cur = kt & 1;
    if (kt < NKT - 1) { // stage next tile into other buffer BEFORE compute
      const int kb = (kt + 1) * (BK * 2);
      char* ad = (char*)As[cur ^ 1] + wid * 2048;
      char* bd = (char*)Bs[cur ^ 1] + wid * 2048;
      gl16(aS0 + kb, ad); gl16(aS1 + kb, ad + 1024);
      gl16(bS0 + kb, bd); gl16(bS1 + kb, bd + 1024);
    }
    bf16x8 af[4], bfv[4];
#pragma unroll
    for (int m = 0; m < 4; m++)
      af[m] = *(const bf16x8*)((const char*)&As[cur][0] +
                               (wr * 64 + m * 16 + (lane & 15)) * 64 + swz16);
#pragma unroll
    for (int n = 0; n < 4; n++) {
      const int c = (n < 2) ? (wc * 32 + n * 16) : (64 + wc * 32 + (n - 2) * 16);
      bfv[n] = *(const bf16x8*)((const char*)&Bs[cur][0] + (c + (lane & 15)) * 64 + swz16);
    }
#pragma unroll
    for (int m = 0; m < 4; m++)
#pragma unroll
      for (int n = 0; n < 4; n++)
        acc[m][n] = __builtin_amdgcn_mfma_f32_16x16x32_bf16(af[m], bfv[n], acc[m][n], 0, 0, 0);
    __syncthreads(); // drains vmcnt(0) too: next buffer staged & visible
  }

  // ---- epilogue: e = exp(logit+gb); fxe = (fx+fb)*e; per-group reduce ----
  const int jA = j0 + wc * 32 + (lane & 15); // cols for n=0 (g) / n=2 (f)
  const float gb0 = g_b[jA], gb1 = g_b[jA + 16];
  const float fb0 = f_b[jA], fb1 = f_b[jA + 16];

  int gmr[4][4];
#pragma unroll
  for (int m = 0; m < 4; m++)
#pragma unroll
    for (int r = 0; r < 4; r++)
      gmr[m][r] = grpS[wr * 64 + m * 16 + (lane >> 4) * 4 + r];

#pragma unroll
  for (int m = 0; m < 4; m++)
#pragma unroll
    for (int r = 0; r < 4; r++) {
      const float e0 = expf(acc[m][0][r] + gb0);
      const float e1 = expf(acc[m][1][r] + gb1);
      const float f0 = acc[m][2][r] + fb0;
      const float f1 = acc[m][3][r] + fb1;
      acc[m][0][r] = e0; acc[m][1][r] = e1;
      acc[m][2][r] = f0 * e0; acc[m][3][r] = f1 * e1;
    }

  const int gLo = grpS[wr * 64], gHi = grpS[wr * 64 + 63];
  for (int g = gLo; g <= gHi; ++g) {
    float v0 = 0.f, v1 = 0.f, v2 = 0.f, v3 = 0.f;
#pragma unroll
    for (int m = 0; m < 4; m++)
#pragma unroll
      for (int r = 0; r < 4; r++)
        if (gmr[m][r] == g) {
          v0 += acc[m][0][r]; v1 += acc[m][1][r];
          v2 += acc[m][2][r]; v3 += acc[m][3][r];
        }
    v0 += __shfl_xor(v0, 16); v0 += __shfl_xor(v0, 32);
    v1 += __shfl_xor(v1, 16); v1 += __shfl_xor(v1, 32);
    v2 += __shfl_xor(v2, 16); v2 += __shfl_xor(v2, 32);
    v3 += __shfl_xor(v3, 16); v3 += __shfl_xor(v3, 32);
    if (lane < 16) {
      float* s1p = s1acc + ((size_t)(b * MG + g)) * D + j0 + wc * 32 + lane;
      float* s2p = s2acc + ((size_t)(b * MG + g)) * D + j0 + wc * 32 + lane;
      atomicAdd(s1p, v0);
      atomicAdd(s1p + 16, v1);
      atomicAdd(s2p, v2);
      atomicAdd(s2p + 16, v3);
    }
  }
}

// ---------------- small GEMM with fused normalize ----------------
__global__ __launch_bounds__(256) void k_gemm2(
    const float* __restrict__ s1, const float* __restrict__ s2,
    const unsigned short* __restrict__ hw, const float* __restrict__ h_b,
    float* __restrict__ outpre) {
  const int tid = threadIdx.x, lane = tid & 63, wid = tid >> 6;
  const int r0 = blockIdx.y * 16;
  const int c0 = blockIdx.x * 64 + wid * 16;
  f32x4 acc = (f32x4){0.f, 0.f, 0.f, 0.f};
  const int arow = r0 + (lane & 15);
  const float* s1p = s1 + (size_t)arow * D + (lane >> 4) * 8;
  const float* s2p = s2 + (size_t)arow * D + (lane >> 4) * 8;
  const unsigned short* bRow = hw + (size_t)(c0 + (lane & 15)) * D + (lane >> 4) * 8;
#pragma unroll
  for (int kt = 0; kt < D / 32; kt++) {
    float4 u0 = *(const float4*)(s1p + kt * 32);
    float4 u1 = *(const float4*)(s1p + kt * 32 + 4);
    float4 w0 = *(const float4*)(s2p + kt * 32);
    float4 w1 = *(const float4*)(s2p + kt * 32 + 4);
    int4 yi;
    yi.x = cvtpk(w0.x * frcp(u0.x + 1e-6f), w0.y * frcp(u0.y + 1e-6f));
    yi.y = cvtpk(w0.z * frcp(u0.z + 1e-6f), w0.w * frcp(u0.w + 1e-6f));
    yi.z = cvtpk(w1.x * frcp(u1.x + 1e-6f), w1.y * frcp(u1.y + 1e-6f));
    yi.w = cvtpk(w1.z * frcp(u1.z + 1e-6f), w1.w * frcp(u1.w + 1e-6f));
    bf16x8 af = *(bf16x8*)&yi;
    bf16x8 bf_ = *(const bf16x8*)(bRow + kt * 32);
    acc = __builtin_amdgcn_mfma_f32_16x16x32_bf16(af, bf_, acc, 0, 0, 0);
  }
  const int col = c0 + (lane & 15);
  const float hb = h_b[col];
#pragma unroll
  for (int r = 0; r < 4; r++) {
    const int row = r0 + (lane >> 4) * 4 + r;
    outpre[(size_t)row * D + col] = acc[r] + hb;
  }
}

// ---------------- gather rows ----------------
__global__ void k_gather(const float* __restrict__ outpre, const int* __restrict__ ii,
                         float* __restrict__ out) {
  const long total4 = (long)RTOT * (D / 4); // 96 float4 per row
  for (long i = blockIdx.x * (long)blockDim.x + threadIdx.x; i < total4;
       i += (long)gridDim.x * blockDim.x) {
    const long row = i / (D / 4);
    const int q = (int)(i % (D / 4));
    const int b = (int)(row >> 14);
    const int n = (int)(row & (NROWS - 1));
    const int g = ii[n];
    ((float4*)out)[i] = ((const float4*)outpre)[((size_t)(b * MG + g)) * (D / 4) + q];
  }
}

extern "C" void kernel_launch(void* const* d_in, const int* in_sizes, int n_in,
                              void* d_out, int out_size, void* d_ws, size_t ws_size,
                              hipStream_t stream) {
  const float* x = (const float*)d_in[0];
  const int* ii = (const int*)d_in[1];
  const float* f_w = (const float*)d_in[2];
  const float* f_b = (const float*)d_in[3];
  const float* g_w = (const float*)d_in[4];
  const float* g_b = (const float*)d_in[5];
  const float* h_w = (const float*)d_in[6];
  const float* h_b = (const float*)d_in[7];
  float* out = (float*)d_out;

  char* ws = (char*)d_ws;
  size_t off = 0;
  auto alloc = [&](size_t bytes) {
    size_t p = off;
    off = (off + bytes + 255) & ~(size_t)255;
    return p;
  };
  unsigned short* xb = (unsigned short*)(ws + alloc((size_t)RTOT * D * 2));
  unsigned short* wt2 = (unsigned short*)(ws + alloc((size_t)NC * D * 2));
  unsigned short* hw = (unsigned short*)(ws + alloc((size_t)D * D * 2));
  float* s1acc = (float*)(ws + alloc((size_t)BATCH * MG * D * 4)); // 3 MB
  float* s2acc = (float*)(ws + alloc((size_t)BATCH * MG * D * 4)); // contiguous after s1acc
  float* outpre = (float*)(ws + alloc((size_t)BATCH * MG * D * 4));
  int* csr_rows = (int*)(ws + alloc((size_t)NROWS * 4));
  int* grp_sorted = (int*)(ws + alloc((size_t)NROWS * 4));

  k_prep<<<dim3(1280), dim3(512), 0, stream>>>(ii, x, g_w, f_w, h_w, xb, wt2, hw,
                                               csr_rows, grp_sorted, s1acc);
  k_gemm1<<<dim3(NJB * NMT), dim3(256), 0, stream>>>(xb, wt2, g_b, f_b, csr_rows,
                                                     grp_sorted, s1acc, s2acc);
  k_gemm2<<<dim3(D / 64, (BATCH * MG) / 16), dim3(256), 0, stream>>>(s1acc, s2acc, hw, h_b,
                                                                     outpre);
  k_gather<<<dim3(4096), dim3(256), 0, stream>>>(outpre, ii, out);
}